// Round 11
// baseline (58.267 us; speedup 1.0000x reference)
//
#include <hip/hip_runtime.h>

#define NM    20
#define NP1   21
#define WVS   2
#define BLK   (WVS * 64)     // 128 threads
#define PPW   2              // points per wave (32 lanes/point)
#define PPB   (WVS * PPW)    // 4 points per block
#define TRI   231            // triangular Q entries per point
#define PTF   273            // LDS floats per point: 231 Q + 21*(Wc,Ws)
#define ROWF  882
#define NPAIR 441

typedef float f32x2 __attribute__((ext_vector_type(2)));

struct Tbl {
    float dprod[NP1];      // INV_SQRT_4PI * prod_{k<=m} (-sqrt((2k+1)/(2k)))  (CS phase)
    float e[NP1];          // sqrt(2m+3)
    float a[NP1][NP1];
    float b[NP1][NP1];
};

constexpr double csqrt_d(double x) {
    double r = x * 0.5 + 0.5;
    for (int i = 0; i < 48; ++i) r = 0.5 * (r + x / r);
    return r;
}

constexpr Tbl make_tbl() {
    Tbl t{};
    const double inv4pi = 0.28209479177387814;
    double dp = inv4pi;
    t.dprod[0] = (float)dp;
    for (int m = 1; m <= NM; ++m) {
        dp *= -csqrt_d((2.0 * m + 1.0) / (2.0 * m));
        t.dprod[m] = (float)dp;
    }
    for (int m = 0; m <= NM; ++m) t.e[m] = (float)csqrt_d(2.0 * m + 3.0);
    for (int m = 0; m <= NM; ++m)
        for (int n = m + 2; n <= NM; ++n) {
            double nn = (double)n * n, mm = (double)m * m;
            t.a[m][n] = (float)csqrt_d((4.0 * nn - 1.0) / (nn - mm));
            t.b[m][n] = (float)csqrt_d((2.0 * n + 1.0) * (n - 1.0 - m) * (n - 1.0 + m) /
                                       ((2.0 * n - 3.0) * (nn - mm)));
        }
    return t;
}

__constant__ Tbl TBL = make_tbl();

// Channel-pair metadata: pidx(8b triangular) | am<<8 (5b) | negRe<<13 | negIm<<14
struct CMap { unsigned short m[448]; };
constexpr CMap make_cmap() {
    CMap c{};
    int ch = 0;
    for (int n = 0; n <= NM; ++n)
        for (int mm = -n; mm <= n; ++mm) {
            int am = mm < 0 ? -mm : mm;
            unsigned pidx = (unsigned)(n * (n + 1) / 2 + am);          // 0..230
            unsigned negRe = (mm < 0 && (am & 1)) ? 1u : 0u;
            unsigned negIm = (mm < 0 && !(am & 1)) ? 1u : 0u;
            c.m[ch++] = (unsigned short)(pidx | (am << 8) | (negRe << 13) | (negIm << 14));
        }
    return c;
}
__constant__ CMap CMAP = make_cmap();

__device__ __forceinline__ void sincos_small(float t, float& sn, float& cs) {
    const float t2 = t * t;
    sn = t * (1.0f + t2 * (-1.0f/6.0f + t2 * (1.0f/120.0f + t2 * (-1.0f/5040.0f))));
    cs = 1.0f + t2 * (-0.5f + t2 * (1.0f/24.0f + t2 * (-1.0f/720.0f + t2 * (1.0f/40320.0f))));
}

// 32-waves/CU design: tiny LDS (1.1KB/pt, Q-triangle + W pairs), VGPR<=64 via
// launch_bounds, cheap-trig ladder, phase 2 = metadata-decode + LDS gathers
// (broadcast/2-way, free) + interleaved nt f32x2 stores. Waves independent.
__global__ __launch_bounds__(BLK, 8) void sph_kernel(const float* __restrict__ theta,
                                                     const float* __restrict__ phi,
                                                     float* __restrict__ out, int npts) {
    __shared__ float sh[PPB][PTF];
    const int tid  = threadIdx.x;
    const int wv   = tid >> 6;
    const int lane = tid & 63;
    const int slot = wv * PPW + (lane >> 5);   // 0..3: point slot in block
    const int col  = lane & 31;                // m-column
    const int gbase = blockIdx.x * PPB;
    const int gpt   = gbase + slot;

    if (gpt < npts && col <= NM) {
        const float th = theta[gpt];
        const float ph = phi[gpt];
        float st, ct, s, x;
        sincos_small(th, st, ct);              // e^{i*theta}
        sincos_small(ph, s, x);                // s = sin(phi), x = cos(phi)
        float* shp = sh[slot];
        const int m = col;

        // W = (s*e^{i*th})^m = (s^m cos(m th), s^m sin(m th)): 5-step binary exp
        float wc = 1.0f, ws = 0.0f;
        float bc = s * ct, bs = s * st;
        int mb = m;
        #pragma unroll
        for (int i = 0; i < 5; ++i) {
            const float nwc = wc * bc - ws * bs;
            const float nws = wc * bs + ws * bc;
            wc = (mb & 1) ? nwc : wc;
            ws = (mb & 1) ? nws : ws;
            mb >>= 1;
            const float t = bc * bc - bs * bs;
            bs = 2.0f * bc * bs;
            bc = t;
        }
        *reinterpret_cast<float2*>(shp + TRI + 2 * m) = make_float2(wc, ws);

        float qb = 0.0f, qa = TBL.dprod[m];    // Q = P / s^m (same recurrence coeffs)
        int trin = m * (m + 1) / 2 + m;        // tri(m)+m
        for (int n = m; n <= NM; ++n) {
            shp[trin] = qa;
            if (n < NM) {
                const float qn = (n == m) ? TBL.e[m] * x * qa
                                          : TBL.a[m][n + 1] * x * qa - TBL.b[m][n + 1] * qb;
                qb = qa; qa = qn;
            }
            trin += n + 1;
        }
    }
    __syncthreads();   // ordering safety only (waves own disjoint slots)

    // Phase 2: per-lane metadata hoisted to 7 regs; 2 points per wave.
    unsigned em[7];
    #pragma unroll
    for (int i = 0; i < 7; ++i) em[i] = CMAP.m[i * 64 + lane];

    #pragma unroll
    for (int q = 0; q < PPW; ++q) {
        const int sq = wv * PPW + q;
        const int g  = gbase + sq;
        if (g >= npts) break;
        const float* S = sh[sq];
        f32x2* dst = reinterpret_cast<f32x2*>(out) + (long long)g * NPAIR;
        #pragma unroll
        for (int i = 0; i < 7; ++i) {
            if (i < 6 || lane < NPAIR - 384) {
                const unsigned e = em[i];
                const float Q  = S[e & 255u];
                const int am   = (e >> 8) & 31u;
                const float wc = S[TRI + 2 * am];
                const float ws = S[TRI + 2 * am + 1];
                float re = Q * wc, im = Q * ws;
                if (e & (1u << 13)) re = -re;
                if (e & (1u << 14)) im = -im;
                f32x2 v = {re, im};
                __builtin_nontemporal_store(v, dst + i * 64 + lane);
            }
        }
    }
}

extern "C" void kernel_launch(void* const* d_in, const int* in_sizes, int n_in,
                              void* d_out, int out_size, void* d_ws, size_t ws_size,
                              hipStream_t stream) {
    const float* theta = (const float*)d_in[0];
    const float* phi   = (const float*)d_in[1];
    float* out = (float*)d_out;
    const int npts = in_sizes[0];
    const int blocks = (npts + PPB - 1) / PPB;
    sph_kernel<<<blocks, BLK, 0, stream>>>(theta, phi, out, npts);
}